// Round 1
// baseline (769.045 us; speedup 1.0000x reference)
//
#include <hip/hip_runtime.h>

#define SC 0.70710678118654752440f

__device__ __forceinline__ int refl(int p, int r) {
    if (p < 0) p = -1 - p;
    else if (p >= r) p = 2 * r - 1 - p;
    return p;
}

// c2q band value on the fly: bands lh=(0,5), hl=(2,3), hh=(1,4)
__device__ __forceinline__ float band_val(const float* __restrict__ yh_nc, int H, int W,
                                          int b1, int b2, int p, int w) {
    int i = p >> 1, j = w >> 1;
    size_t o1 = (((size_t)b1 * H + i) * W + j) * 2;
    size_t o2 = (((size_t)b2 * H + i) * W + j) * 2;
    float v;
    if ((p & 1) == 0) {
        int comp = (w & 1);
        v = (yh_nc[o1 + comp] + yh_nc[o2 + comp]) * SC;
    } else {
        if ((w & 1) == 0) v = (yh_nc[o1 + 1] - yh_nc[o2 + 1]) * SC;
        else              v = (yh_nc[o2 + 0] - yh_nc[o1 + 0]) * SC;
    }
    return v;
}

// Column-pass for _inv_j2plus level: y1 = colifilt(ll,g0b,g0a,F) + colifilt(lh,g1b,g1a,T)
//                                    y2 = colifilt(hl,g0b,g0a,F) + colifilt(hh,g1b,g1a,T)
// ll: (NC, 2H, 2W); yh: (NC, 6, H, W, 2); y1,y2: (NC, 4H, 2W)
__global__ void j2_col_kernel(const float* __restrict__ ll,
                              const float* __restrict__ yh,
                              const float* __restrict__ g0a, const float* __restrict__ g0b,
                              const float* __restrict__ g1a, const float* __restrict__ g1b,
                              float* __restrict__ y1, float* __restrict__ y2,
                              int NC, int H, int W) {
    const int r = 2 * H, c = 2 * W;
    const int R2 = 2 * r;
    size_t idx = (size_t)blockIdx.x * blockDim.x + threadIdx.x;
    size_t total = (size_t)NC * R2 * c;
    if (idx >= total) return;
    int w  = (int)(idx % c);
    int o  = (int)((idx / c) % R2);
    int nc = (int)(idx / ((size_t)c * R2));
    int q = o >> 2, s = o & 3;
    int base = 8 + ((s >> 1) & 1);
    const float* Fl = (s & 1) ? g0a : g0b;
    const float* Fh = (s & 1) ? g1a : g1b;
    int dl = ((s & 1) == 0) ? -4 : -3;   // lowpass (highpass=False) gather offset
    int dh = -7 - dl;                    // highpass gather offset (swapped)
    const float* ll_nc = ll + (size_t)nc * r * c;
    const float* yh_nc = yh + (size_t)nc * 6 * H * W * 2;
    float acc1 = 0.f, acc2 = 0.f;
#pragma unroll
    for (int k = 0; k < 5; ++k) {
        float cl = Fl[base - 2 * k];
        float ch = Fh[base - 2 * k];
        int pl = refl(2 * (q + k) + dl, r);
        int ph = refl(2 * (q + k) + dh, r);
        acc1 = fmaf(cl, ll_nc[(size_t)pl * c + w], acc1);
        acc1 = fmaf(ch, band_val(yh_nc, H, W, 0, 5, ph, w), acc1);
        acc2 = fmaf(cl, band_val(yh_nc, H, W, 2, 3, pl, w), acc2);
        acc2 = fmaf(ch, band_val(yh_nc, H, W, 1, 4, ph, w), acc2);
    }
    y1[idx] = acc1;
    y2[idx] = acc2;
}

// Row-pass for _inv_j2plus level: out = rowifilt(y1,g0b,g0a,F) + rowifilt(y2,g1b,g1a,T)
// y1,y2: (NC, R, cIn); out: (NC, R, 2*cIn)
__global__ void j2_row_kernel(const float* __restrict__ y1, const float* __restrict__ y2,
                              const float* __restrict__ g0a, const float* __restrict__ g0b,
                              const float* __restrict__ g1a, const float* __restrict__ g1b,
                              float* __restrict__ out,
                              int NC, int R, int cIn) {
    const int cOut = 2 * cIn;
    size_t idx = (size_t)blockIdx.x * blockDim.x + threadIdx.x;
    size_t total = (size_t)NC * R * cOut;
    if (idx >= total) return;
    int ow = (int)(idx % cOut);
    size_t rowIdx = idx / cOut;  // nc*R + row
    int q = ow >> 2, s = ow & 3;
    int base = 8 + ((s >> 1) & 1);
    const float* Fl = (s & 1) ? g0a : g0b;
    const float* Fh = (s & 1) ? g1a : g1b;
    int dl = ((s & 1) == 0) ? -4 : -3;
    int dh = -7 - dl;
    const float* y1r = y1 + rowIdx * cIn;
    const float* y2r = y2 + rowIdx * cIn;
    float acc = 0.f;
#pragma unroll
    for (int k = 0; k < 5; ++k) {
        float cl = Fl[base - 2 * k];
        float ch = Fh[base - 2 * k];
        acc = fmaf(cl, y1r[refl(2 * (q + k) + dl, cIn)], acc);
        acc = fmaf(ch, y2r[refl(2 * (q + k) + dh, cIn)], acc);
    }
    out[idx] = acc;
}

// Column-pass for _inv_j1: y1 = colfilter(ll,g0o)+colfilter(lh,g1o)
//                          y2 = colfilter(hl,g0o)+colfilter(hh,g1o)
// ll: (NC, 2H, 2W); yh: (NC,6,H,W,2); y1,y2: (NC, 2H, 2W)
__global__ void j1_col_kernel(const float* __restrict__ ll, const float* __restrict__ yh,
                              const float* __restrict__ g0o, const float* __restrict__ g1o,
                              float* __restrict__ y1, float* __restrict__ y2,
                              int NC, int H, int W) {
    const int r = 2 * H, c = 2 * W;
    size_t idx = (size_t)blockIdx.x * blockDim.x + threadIdx.x;
    size_t total = (size_t)NC * r * c;
    if (idx >= total) return;
    int w  = (int)(idx % c);
    int i  = (int)((idx / c) % r);
    int nc = (int)(idx / ((size_t)c * r));
    const float* ll_nc = ll + (size_t)nc * r * c;
    const float* yh_nc = yh + (size_t)nc * 6 * H * W * 2;
    float acc1 = 0.f, acc2 = 0.f;
#pragma unroll
    for (int k = 0; k < 7; ++k) {
        float cf = g0o[6 - k];
        int p = refl(i - 3 + k, r);
        acc1 = fmaf(cf, ll_nc[(size_t)p * c + w], acc1);
        acc2 = fmaf(cf, band_val(yh_nc, H, W, 2, 3, p, w), acc2);
    }
#pragma unroll
    for (int k = 0; k < 5; ++k) {
        float cf = g1o[4 - k];
        int p = refl(i - 2 + k, r);
        acc1 = fmaf(cf, band_val(yh_nc, H, W, 0, 5, p, w), acc1);
        acc2 = fmaf(cf, band_val(yh_nc, H, W, 1, 4, p, w), acc2);
    }
    y1[idx] = acc1;
    y2[idx] = acc2;
}

// Row-pass for _inv_j1: out = rowfilter(y1,g0o) + rowfilter(y2,g1o); shapes (NC,R,c)
__global__ void j1_row_kernel(const float* __restrict__ y1, const float* __restrict__ y2,
                              const float* __restrict__ g0o, const float* __restrict__ g1o,
                              float* __restrict__ out, int NC, int R, int c) {
    size_t idx = (size_t)blockIdx.x * blockDim.x + threadIdx.x;
    size_t total = (size_t)NC * R * c;
    if (idx >= total) return;
    int j = (int)(idx % c);
    size_t rowIdx = idx / c;
    const float* y1r = y1 + rowIdx * c;
    const float* y2r = y2 + rowIdx * c;
    float acc = 0.f;
#pragma unroll
    for (int k = 0; k < 7; ++k)
        acc = fmaf(g0o[6 - k], y1r[refl(j - 3 + k, c)], acc);
#pragma unroll
    for (int k = 0; k < 5; ++k)
        acc = fmaf(g1o[4 - k], y2r[refl(j - 2 + k, c)], acc);
    out[idx] = acc;
}

extern "C" void kernel_launch(void* const* d_in, const int* in_sizes, int n_in,
                              void* d_out, int out_size, void* d_ws, size_t ws_size,
                              hipStream_t stream) {
    const float* yl  = (const float*)d_in[0];
    const float* yh1 = (const float*)d_in[1];
    const float* yh2 = (const float*)d_in[2];
    const float* yh3 = (const float*)d_in[3];
    const float* g0o = (const float*)d_in[4];
    const float* g1o = (const float*)d_in[5];
    const float* g0a = (const float*)d_in[6];
    const float* g0b = (const float*)d_in[7];
    const float* g1a = (const float*)d_in[8];
    const float* g1b = (const float*)d_in[9];
    float* out = (float*)d_out;

    const int NC = 4 * 64;
    float* llA = (float*)d_ws;                       // (NC,128,128)
    float* t1  = llA + (size_t)NC * 128 * 128;       // up to (NC,256,256)
    float* t2  = t1 + (size_t)NC * 256 * 256;        // up to (NC,256,256)

    const int BLK = 256;
    auto gs = [](size_t n, int blk) { return (unsigned)((n + (size_t)blk - 1) / blk); };

    // ---- Level 3: yl (NC,64,64) + yh3 (NC,6,32,32,2) -> llA (NC,128,128)
    {
        const int H = 32, W = 32;
        size_t nCol = (size_t)NC * (4 * H) * (2 * W);
        j2_col_kernel<<<gs(nCol, BLK), BLK, 0, stream>>>(yl, yh3, g0a, g0b, g1a, g1b,
                                                         t1, t2, NC, H, W);
        size_t nRow = (size_t)NC * (4 * H) * (4 * W);
        j2_row_kernel<<<gs(nRow, BLK), BLK, 0, stream>>>(t1, t2, g0a, g0b, g1a, g1b,
                                                         llA, NC, 4 * H, 2 * W);
    }
    // ---- Level 2: llA + yh2 (NC,6,64,64,2) -> out (used as llB, (NC,256,256))
    {
        const int H = 64, W = 64;
        size_t nCol = (size_t)NC * (4 * H) * (2 * W);
        j2_col_kernel<<<gs(nCol, BLK), BLK, 0, stream>>>(llA, yh2, g0a, g0b, g1a, g1b,
                                                         t1, t2, NC, H, W);
        size_t nRow = (size_t)NC * (4 * H) * (4 * W);
        j2_row_kernel<<<gs(nRow, BLK), BLK, 0, stream>>>(t1, t2, g0a, g0b, g1a, g1b,
                                                         out, NC, 4 * H, 2 * W);
    }
    // ---- Level 1 (j1): out (NC,256,256) + yh1 (NC,6,128,128,2) -> out
    {
        const int H = 128, W = 128;
        size_t n = (size_t)NC * (2 * H) * (2 * W);
        j1_col_kernel<<<gs(n, BLK), BLK, 0, stream>>>(out, yh1, g0o, g1o, t1, t2, NC, H, W);
        j1_row_kernel<<<gs(n, BLK), BLK, 0, stream>>>(t1, t2, g0o, g1o, out, NC, 2 * H, 2 * W);
    }
}